// Round 1
// baseline (205.380 us; speedup 1.0000x reference)
//
#include <hip/hip_runtime.h>
#include <hip/hip_bf16.h>

// Problem sizes (fixed by the reference): B=2, T=512, D=768, U=768
#define BB 2
#define TT 512
#define DD 768
#define UU 768

static __device__ __forceinline__ float fexp2(float x) { return __builtin_amdgcn_exp2f(x); }
static __device__ __forceinline__ float frcp(float x)  { return __builtin_amdgcn_rcpf(x); }

// ---------------------------------------------------------------------------
// Kernel A: projections. out = f(x @ Bmat), 64x64 tile, BK=16, 256 threads,
// 4x4 micro-tile per thread.
//   mode 0 (z=0): wxs[r][u]    = (x@W)[r][u] * c           (c = 2*log2(e))
//   mode 1 (z=1): uxT[b][u][j] = ((x@U)[b*T+j][u] + b_u[u]) * c   (transposed)
// ---------------------------------------------------------------------------
__global__ __launch_bounds__(256) void gemm_proj(
    const float* __restrict__ x,
    const float* __restrict__ Wm,
    const float* __restrict__ Um,
    const float* __restrict__ bu,
    float* __restrict__ wxs,
    float* __restrict__ uxT)
{
    const int mode = blockIdx.z;
    const float* __restrict__ Bm = mode ? Um : Wm;

    __shared__ float Ast[16][64];   // [k][m] (transposed A tile)
    __shared__ float Bs[16][64];    // [k][n]

    const int tid = threadIdx.x;
    const int tx = tid & 15;        // n quad
    const int ty = tid >> 4;        // m quad
    const int by = blockIdx.y;      // m tile (16)
    const int bn = blockIdx.x;      // n tile (12)

    // staging indices
    const int ar  = tid >> 2;         // row within A tile (0..63)
    const int ak4 = (tid & 3) << 2;   // k quad within A tile
    const int bk  = tid >> 4;         // k row within B tile (0..15)
    const int bn4 = (tid & 15) << 2;  // n quad within B tile

    float acc[4][4] = {};

    for (int k0 = 0; k0 < DD; k0 += 16) {
        float4 a4 = *(const float4*)(x  + (by * 64 + ar) * DD + k0 + ak4);
        float4 b4 = *(const float4*)(Bm + (k0 + bk) * UU + bn * 64 + bn4);
        __syncthreads();
        Ast[ak4 + 0][ar] = a4.x;
        Ast[ak4 + 1][ar] = a4.y;
        Ast[ak4 + 2][ar] = a4.z;
        Ast[ak4 + 3][ar] = a4.w;
        *(float4*)&Bs[bk][bn4] = b4;
        __syncthreads();
        #pragma unroll
        for (int kk = 0; kk < 16; ++kk) {
            float4 av = *(const float4*)&Ast[kk][ty << 2];
            float4 bv = *(const float4*)&Bs[kk][tx << 2];
            float aa[4] = {av.x, av.y, av.z, av.w};
            float bb2[4] = {bv.x, bv.y, bv.z, bv.w};
            #pragma unroll
            for (int i = 0; i < 4; ++i)
                #pragma unroll
                for (int j = 0; j < 4; ++j)
                    acc[i][j] = fmaf(aa[i], bb2[j], acc[i][j]);
        }
    }

    const float c = 2.8853900817779268f;  // 2*log2(e)
    if (mode == 0) {
        #pragma unroll
        for (int i = 0; i < 4; ++i) {
            const int m = by * 64 + (ty << 2) + i;
            const int n = bn * 64 + (tx << 2);
            float4 o;
            o.x = acc[i][0] * c; o.y = acc[i][1] * c;
            o.z = acc[i][2] * c; o.w = acc[i][3] * c;
            *(float4*)(wxs + m * UU + n) = o;
        }
    } else {
        #pragma unroll
        for (int i = 0; i < 4; ++i) {
            const int m = by * 64 + (ty << 2) + i;
            const int b = m >> 9;       // m / T
            const int j = m & 511;      // m % T
            #pragma unroll
            for (int jj = 0; jj < 4; ++jj) {
                const int n = bn * 64 + (tx << 2) + jj;
                uxT[(size_t)b * UU * TT + (size_t)n * TT + j] = (acc[i][jj] + bu[n]) * c;
            }
        }
    }
}

// ---------------------------------------------------------------------------
// Kernel B: fused e / softmax / PV.
// Grid: 512 blocks (2 query rows each), 256 threads = 4 waves.
// Wave w covers j in [w*128, w*128+128) (two 64-lane groups).
// e[i][j] = sum_u V[u] * tanh-form using prescaled wxs/uxT:
//   tanh = 1 - 2*rcp(1 + exp2(wxs'+uxT'))
// ---------------------------------------------------------------------------
__global__ __launch_bounds__(256) void attn_fused(
    const float* __restrict__ x,
    const float* __restrict__ V_a,
    const float* __restrict__ wxs,
    const float* __restrict__ uxT,
    float* __restrict__ out)
{
    __shared__ float wx_s[2 * UU];      // the block's 2 query rows (prescaled)
    __shared__ float v_s[UU];
    __shared__ float at_s[2][TT];       // softmax weights
    __shared__ float red[2][2][4];      // [phase][ii][wave]

    const int tid  = threadIdx.x;
    const int lane = tid & 63;
    const int w    = tid >> 6;
    const int blk  = blockIdx.x;
    const int r0   = blk * 2;           // global query row (b*T + i)
    const int b    = r0 >> 9;

    // stage 2 wx rows (contiguous 1536 floats) + V
    for (int t = tid; t < 384; t += 256)
        *(float4*)&wx_s[t * 4] = *(const float4*)(wxs + r0 * UU + t * 4);
    for (int t = tid; t < 192; t += 256)
        *(float4*)&v_s[t * 4] = *(const float4*)(V_a + t * 4);
    __syncthreads();

    const int j0 = w * 128 + lane;      // first j handled by this lane
    const float* __restrict__ uxb = uxT + (size_t)b * UU * TT + j0;

    float a00 = 0.f, a01 = 0.f, a10 = 0.f, a11 = 0.f;
    #pragma unroll 4
    for (int u = 0; u < UU; ++u) {
        const float u0 = uxb[u * TT];
        const float u1 = uxb[u * TT + 64];
        const float vv = v_s[u];
        const float w0 = wx_s[u];
        const float w1 = wx_s[UU + u];
        const float e0 = fexp2(w0 + u0);
        const float e1 = fexp2(w0 + u1);
        const float e2 = fexp2(w1 + u0);
        const float e3 = fexp2(w1 + u1);
        const float q0 = frcp(1.f + e0);
        const float q1 = frcp(1.f + e1);
        const float q2 = frcp(1.f + e2);
        const float q3 = frcp(1.f + e3);
        a00 = fmaf(vv, fmaf(-2.f, q0, 1.f), a00);
        a01 = fmaf(vv, fmaf(-2.f, q1, 1.f), a01);
        a10 = fmaf(vv, fmaf(-2.f, q2, 1.f), a10);
        a11 = fmaf(vv, fmaf(-2.f, q3, 1.f), a11);
    }

    // ---- softmax over j (cross-wave) ----
    float m0 = fmaxf(a00, a01), m1 = fmaxf(a10, a11);
    #pragma unroll
    for (int off = 32; off; off >>= 1) {
        m0 = fmaxf(m0, __shfl_xor(m0, off, 64));
        m1 = fmaxf(m1, __shfl_xor(m1, off, 64));
    }
    if (lane == 0) { red[0][0][w] = m0; red[0][1][w] = m1; }
    __syncthreads();
    const float M0 = fmaxf(fmaxf(red[0][0][0], red[0][0][1]), fmaxf(red[0][0][2], red[0][0][3]));
    const float M1 = fmaxf(fmaxf(red[0][1][0], red[0][1][1]), fmaxf(red[0][1][2], red[0][1][3]));

    const float L2E = 1.4426950408889634f;
    const float p00 = fexp2((a00 - M0) * L2E);
    const float p01 = fexp2((a01 - M0) * L2E);
    const float p10 = fexp2((a10 - M1) * L2E);
    const float p11 = fexp2((a11 - M1) * L2E);
    float s0 = p00 + p01, s1 = p10 + p11;
    #pragma unroll
    for (int off = 32; off; off >>= 1) {
        s0 += __shfl_xor(s0, off, 64);
        s1 += __shfl_xor(s1, off, 64);
    }
    if (lane == 0) { red[1][0][w] = s0; red[1][1][w] = s1; }
    __syncthreads();
    const float S0 = red[1][0][0] + red[1][0][1] + red[1][0][2] + red[1][0][3];
    const float S1 = red[1][1][0] + red[1][1][1] + red[1][1][2] + red[1][1][3];
    const float i0 = frcp(S0);
    const float i1 = frcp(S1);
    at_s[0][j0]      = p00 * i0;
    at_s[0][j0 + 64] = p01 * i0;
    at_s[1][j0]      = p10 * i1;
    at_s[1][j0 + 64] = p11 * i1;
    __syncthreads();

    // ---- PV: context[i][d] = sum_j at[i][j] * x[b][j][d] ----
    // wave w covers d = w*192 + {0,64,128} + lane
    const float* __restrict__ xb = x + (size_t)b * TT * DD;
    const int d0 = w * 192 + lane;
    float c00 = 0.f, c01 = 0.f, c02 = 0.f, c10 = 0.f, c11 = 0.f, c12 = 0.f;
    #pragma unroll 4
    for (int j = 0; j < TT; ++j) {
        const float at0 = at_s[0][j];
        const float at1 = at_s[1][j];
        const float* __restrict__ xr = xb + j * DD + d0;
        const float x0 = xr[0];
        const float x1 = xr[64];
        const float x2 = xr[128];
        c00 = fmaf(at0, x0, c00);
        c01 = fmaf(at0, x1, c01);
        c02 = fmaf(at0, x2, c02);
        c10 = fmaf(at1, x0, c10);
        c11 = fmaf(at1, x1, c11);
        c12 = fmaf(at1, x2, c12);
    }
    float* o0 = out + (size_t)r0 * DD + d0;
    o0[0] = c00; o0[64] = c01; o0[128] = c02;
    float* o1 = out + (size_t)(r0 + 1) * DD + d0;
    o1[0] = c10; o1[64] = c11; o1[128] = c12;
}

// ---------------------------------------------------------------------------
extern "C" void kernel_launch(void* const* d_in, const int* in_sizes, int n_in,
                              void* d_out, int out_size, void* d_ws, size_t ws_size,
                              hipStream_t stream)
{
    const float* x   = (const float*)d_in[0];  // (B,T,D)
    const float* V_a = (const float*)d_in[1];  // (U,)
    const float* U_a = (const float*)d_in[2];  // (D,U)
    const float* b_u = (const float*)d_in[3];  // (U,)
    const float* W_a = (const float*)d_in[4];  // (D,U)
    float* out = (float*)d_out;                // (B,T,D)

    float* wxs = (float*)d_ws;                       // (B*T, U) prescaled, 3 MB
    float* uxT = wxs + (size_t)BB * TT * UU;         // (B, U, T) prescaled, 3 MB

    dim3 gA(UU / 64, (BB * TT) / 64, 2);             // (12, 16, 2)
    hipLaunchKernelGGL(gemm_proj, gA, dim3(256), 0, stream, x, W_a, U_a, b_u, wxs, uxT);

    hipLaunchKernelGGL(attn_fused, dim3((BB * TT) / 2), dim3(256), 0, stream,
                       x, V_a, wxs, uxT, out);
}

// Round 2
// 182.041 us; speedup vs baseline: 1.1282x; 1.1282x over previous
//
#include <hip/hip_runtime.h>
#include <hip/hip_bf16.h>

// Problem sizes (fixed by the reference): B=2, T=512, D=768, U=768
#define BB 2
#define TT 512
#define DD 768
#define UU 768

static __device__ __forceinline__ float fexp2(float x) { return __builtin_amdgcn_exp2f(x); }
static __device__ __forceinline__ float frcp(float x)  { return __builtin_amdgcn_rcpf(x); }

// c = 2*log2(e): exp2(c*z) = e^{2z}
#define CC 2.8853900817779268f

// ---------------------------------------------------------------------------
// Kernel A: projections. 64x64 tile, BK=16, 256 threads, 4x4 micro-tile.
//   mode 0 (z=0): EW[r][u]     = exp2(c * (x@W)[r][u])
//   mode 1 (z=1): EUT[b][u][j] = exp2(c * ((x@U)[b*T+j][u] + b_u[u]))  (transposed)
// ---------------------------------------------------------------------------
__global__ __launch_bounds__(256) void gemm_proj(
    const float* __restrict__ x,
    const float* __restrict__ Wm,
    const float* __restrict__ Um,
    const float* __restrict__ bu,
    float* __restrict__ EW,
    float* __restrict__ EUT)
{
    const int mode = blockIdx.z;
    const float* __restrict__ Bm = mode ? Um : Wm;

    __shared__ float Ast[16][64];   // [k][m] (transposed A tile)
    __shared__ float Bs[16][64];    // [k][n]

    const int tid = threadIdx.x;
    const int tx = tid & 15;        // n quad
    const int ty = tid >> 4;        // m quad
    const int by = blockIdx.y;      // m tile (16)
    const int bn = blockIdx.x;      // n tile (12)

    const int ar  = tid >> 2;         // row within A tile (0..63)
    const int ak4 = (tid & 3) << 2;   // k quad within A tile
    const int bk  = tid >> 4;         // k row within B tile (0..15)
    const int bn4 = (tid & 15) << 2;  // n quad within B tile

    float acc[4][4] = {};

    for (int k0 = 0; k0 < DD; k0 += 16) {
        float4 a4 = *(const float4*)(x  + (by * 64 + ar) * DD + k0 + ak4);
        float4 b4 = *(const float4*)(Bm + (k0 + bk) * UU + bn * 64 + bn4);
        __syncthreads();
        Ast[ak4 + 0][ar] = a4.x;
        Ast[ak4 + 1][ar] = a4.y;
        Ast[ak4 + 2][ar] = a4.z;
        Ast[ak4 + 3][ar] = a4.w;
        *(float4*)&Bs[bk][bn4] = b4;
        __syncthreads();
        #pragma unroll
        for (int kk = 0; kk < 16; ++kk) {
            float4 av = *(const float4*)&Ast[kk][ty << 2];
            float4 bv = *(const float4*)&Bs[kk][tx << 2];
            float aa[4] = {av.x, av.y, av.z, av.w};
            float bb2[4] = {bv.x, bv.y, bv.z, bv.w};
            #pragma unroll
            for (int i = 0; i < 4; ++i)
                #pragma unroll
                for (int j = 0; j < 4; ++j)
                    acc[i][j] = fmaf(aa[i], bb2[j], acc[i][j]);
        }
    }

    if (mode == 0) {
        #pragma unroll
        for (int i = 0; i < 4; ++i) {
            const int m = by * 64 + (ty << 2) + i;
            const int n = bn * 64 + (tx << 2);
            float4 o;
            o.x = fexp2(acc[i][0] * CC);
            o.y = fexp2(acc[i][1] * CC);
            o.z = fexp2(acc[i][2] * CC);
            o.w = fexp2(acc[i][3] * CC);
            *(float4*)(EW + m * UU + n) = o;
        }
    } else {
        #pragma unroll
        for (int i = 0; i < 4; ++i) {
            const int m = by * 64 + (ty << 2) + i;
            const int b = m >> 9;       // m / T
            const int j = m & 511;      // m % T
            #pragma unroll
            for (int jj = 0; jj < 4; ++jj) {
                const int n = bn * 64 + (tx << 2) + jj;
                EUT[(size_t)b * UU * TT + (size_t)n * TT + j] =
                    fexp2((acc[i][jj] + bu[n]) * CC);
            }
        }
    }
}

// ---------------------------------------------------------------------------
// Kernel B: fused e / softmax / PV.
// 512 blocks x 512 threads (8 waves). Block handles 2 query rows; lane owns
// j = tid. Inner loop (per u): 1 vector load (EU), 3 scalar loads (EW0, EW1,
// V — wave-uniform), q = rcp(fma(EU,EW,1)), acc = fma(v,q,acc).
// e = SV - 2*acc; SV cancels in softmax, so softmax uses min(acc):
//   p = exp2(c * (min_acc - acc)).
// ---------------------------------------------------------------------------
__global__ __launch_bounds__(512) void attn_fused(
    const float* __restrict__ x,
    const float* __restrict__ V_a,
    const float* __restrict__ EW,
    const float* __restrict__ EUT,
    float* __restrict__ out)
{
    __shared__ float2 at_s[TT];
    __shared__ float red[2][2][8];

    const int tid  = threadIdx.x;
    const int lane = tid & 63;
    const int w    = tid >> 6;

    // XCD-bijective swizzle (512 blocks = 8 XCDs x 64): keeps one batch's
    // EU + x (~3 MB) resident per XCD L2.
    const int bid = blockIdx.x;
    const int blk = (bid & 7) * 64 + (bid >> 3);

    const int r0 = blk * 2;             // global query row (b*T + i)
    const int b  = r0 >> 9;

    const float* __restrict__ ew0 = EW + (size_t)r0 * UU;       // uniform -> s_load
    const float* __restrict__ ew1 = ew0 + UU;                   // uniform -> s_load
    const float* __restrict__ eu  = EUT + (size_t)b * UU * TT + tid;

    float acc0 = 0.f, acc1 = 0.f;
    #pragma unroll 8
    for (int u = 0; u < UU; ++u) {
        const float E  = eu[(size_t)u * TT];
        const float s0 = ew0[u];
        const float s1 = ew1[u];
        const float vv = V_a[u];
        const float q0 = frcp(fmaf(E, s0, 1.f));
        const float q1 = frcp(fmaf(E, s1, 1.f));
        acc0 = fmaf(vv, q0, acc0);
        acc1 = fmaf(vv, q1, acc1);
    }

    // ---- softmax over j (8-wave reduce); e-max  <->  acc-min ----
    float m0 = acc0, m1 = acc1;
    #pragma unroll
    for (int off = 32; off; off >>= 1) {
        m0 = fminf(m0, __shfl_xor(m0, off, 64));
        m1 = fminf(m1, __shfl_xor(m1, off, 64));
    }
    if (lane == 0) { red[0][0][w] = m0; red[0][1][w] = m1; }
    __syncthreads();
    float M0 = red[0][0][0], M1 = red[0][1][0];
    #pragma unroll
    for (int k = 1; k < 8; ++k) {
        M0 = fminf(M0, red[0][0][k]);
        M1 = fminf(M1, red[0][1][k]);
    }

    const float p0 = fexp2(CC * (M0 - acc0));
    const float p1 = fexp2(CC * (M1 - acc1));
    float s0 = p0, s1 = p1;
    #pragma unroll
    for (int off = 32; off; off >>= 1) {
        s0 += __shfl_xor(s0, off, 64);
        s1 += __shfl_xor(s1, off, 64);
    }
    if (lane == 0) { red[1][0][w] = s0; red[1][1][w] = s1; }
    __syncthreads();
    float S0 = red[1][0][0], S1 = red[1][1][0];
    #pragma unroll
    for (int k = 1; k < 8; ++k) {
        S0 += red[1][0][k];
        S1 += red[1][1][k];
    }
    at_s[tid] = make_float2(p0 * frcp(S0), p1 * frcp(S1));
    __syncthreads();

    // ---- PV: context[r][d] = sum_j at[r][j] * x[b][j][d] ----
    const float* __restrict__ xb = x + (size_t)b * TT * DD;
    const int d0 = tid;
    float c00 = 0.f, c10 = 0.f;
    #pragma unroll 4
    for (int j = 0; j < TT; ++j) {
        const float2 a = at_s[j];
        const float x0 = xb[j * DD + d0];
        c00 = fmaf(a.x, x0, c00);
        c10 = fmaf(a.y, x0, c10);
    }
    out[(size_t)r0 * DD + d0]       = c00;
    out[(size_t)(r0 + 1) * DD + d0] = c10;

    if (tid < 256) {                    // waves 0-3: d1 = tid + 512
        const int d1 = tid + 512;
        float c01 = 0.f, c11 = 0.f;
        #pragma unroll 4
        for (int j = 0; j < TT; ++j) {
            const float2 a = at_s[j];
            const float x1 = xb[j * DD + d1];
            c01 = fmaf(a.x, x1, c01);
            c11 = fmaf(a.y, x1, c11);
        }
        out[(size_t)r0 * DD + d1]       = c01;
        out[(size_t)(r0 + 1) * DD + d1] = c11;
    }
}

// ---------------------------------------------------------------------------
extern "C" void kernel_launch(void* const* d_in, const int* in_sizes, int n_in,
                              void* d_out, int out_size, void* d_ws, size_t ws_size,
                              hipStream_t stream)
{
    const float* x   = (const float*)d_in[0];  // (B,T,D)
    const float* V_a = (const float*)d_in[1];  // (U,)
    const float* U_a = (const float*)d_in[2];  // (D,U)
    const float* b_u = (const float*)d_in[3];  // (U,)
    const float* W_a = (const float*)d_in[4];  // (D,U)
    float* out = (float*)d_out;                // (B,T,D)

    float* EW  = (float*)d_ws;                       // (B*T, U), 3 MB
    float* EUT = EW + (size_t)BB * TT * UU;          // (B, U, T), 3 MB

    dim3 gA(UU / 64, (BB * TT) / 64, 2);             // (12, 16, 2)
    hipLaunchKernelGGL(gemm_proj, gA, dim3(256), 0, stream, x, W_a, U_a, b_u, EW, EUT);

    hipLaunchKernelGGL(attn_fused, dim3(BB * TT / 2), dim3(512), 0, stream,
                       x, V_a, EW, EUT, out);
}